// Round 9
// baseline (443.812 us; speedup 1.0000x reference)
//
#include <hip/hip_runtime.h>
#include <math.h>

typedef unsigned short ushort_t;
typedef __bf16 bf16x8 __attribute__((ext_vector_type(8)));
typedef ushort_t ushort8v __attribute__((ext_vector_type(8)));
typedef float f32x4 __attribute__((ext_vector_type(4)));

#define B_SZ   4
#define SEQ    8192
#define M_ROWS (B_SZ * SEQ)   // 32768
#define CH     128
#define NC     (SEQ / CH)     // 64

__device__ __forceinline__ ushort_t f2bf(float f) {
    unsigned u = __float_as_uint(f);
    u = u + 0x7fffu + ((u >> 16) & 1u);
    return (ushort_t)(u >> 16);
}
__device__ __forceinline__ float bf2f(ushort_t b) {
    return __uint_as_float(((unsigned)b) << 16);
}

__device__ __forceinline__ void load16_lds(const void* g, void* l) {
    __builtin_amdgcn_global_load_lds(
        (const __attribute__((address_space(1))) unsigned int*)g,
        (__attribute__((address_space(3))) unsigned int*)l, 16, 0, 0);
}

__device__ __forceinline__ bf16x8 ldfrag(const ushort_t* p) {
    union { ushort8v u; bf16x8 b; } cv;
    cv.u = *(const ushort8v*)p;
    return cv.b;
}

__device__ __forceinline__ float2 cmul(float2 a, float2 b) {
    return make_float2(a.x * b.x - a.y * b.y, a.x * b.y + a.y * b.x);
}

// ---------------------------------------------------------------------------
// prep (unchanged, verified).
__global__ void prep_kernel(const float* __restrict__ Lre,
                            const float* __restrict__ Lim,
                            const float* __restrict__ ldt,
                            const float* __restrict__ Bre,
                            const float* __restrict__ Bim,
                            const float* __restrict__ Cre,
                            const float* __restrict__ Cim,
                            float* __restrict__ abar,
                            float* __restrict__ PW,
                            ushort_t* __restrict__ Bmat,
                            ushort_t* __restrict__ Cmat) {
    int idx = blockIdx.x * 256 + threadIdx.x;   // 0 .. 262143
    int h = idx & 511;
    int p = (idx >> 9) & 255;
    int d = idx >> 17;
    int ip = d * 256 + p;
    float lr = Lre[ip], li = Lim[ip];
    float dt = expf(ldt[ip]);
    float e   = expf(lr * dt);
    float ang = li * dt;
    float ar = e * cosf(ang), ai = e * sinf(ang);
    float nr = ar - 1.0f, ni = ai;
    float den = lr * lr + li * li;
    float cr = (nr * lr + ni * li) / den;
    float ci = (ni * lr - nr * li) / den;
    float br = Bre[idx], bi = Bim[idx];
    Bmat[(d * 512 + 2 * p) * 512 + h]     = f2bf(cr * br - ci * bi);
    Bmat[(d * 512 + 2 * p + 1) * 512 + h] = f2bf(cr * bi + ci * br);
    if (h == 0) {
        int oo = d * 512 + 2 * p;
        abar[oo] = ar;  abar[oo + 1] = ai;
        float2 a1 = make_float2(ar, ai);
        float2 a2 = cmul(a1, a1);
        float2 a4 = cmul(a2, a2);
        float2 a8 = cmul(a4, a4);
        float2 a16 = cmul(a8, a8);
        float2 a32 = cmul(a16, a16);
        float2 a64 = cmul(a32, a32);
        int q = d * 256 + p;
        PW[q * 8 + 0] = a1.x;  PW[q * 8 + 1] = a1.y;
        PW[q * 8 + 2] = a4.x;  PW[q * 8 + 3] = a4.y;
        PW[q * 8 + 4] = a16.x; PW[q * 8 + 5] = a16.y;
        PW[q * 8 + 6] = a64.x; PW[q * 8 + 7] = a64.y;
    }
    int p2 = idx & 255;
    int h2 = (idx >> 8) & 511;
    int d2 = idx >> 17;
    Cmat[h2 * 1024 + d2 * 512 + 2 * p2]     = f2bf(Cre[idx]);
    Cmat[h2 * 1024 + d2 * 512 + 2 * p2 + 1] = f2bf(-Cim[idx]);
}

// ---------------------------------------------------------------------------
// GEMM1 (unchanged, verified): SB = bf16(x) * Bm^T, 128x256 tile, BK=32 dbuf,
// reg-staged A from f32 x, gload_lds B, fused 64-row carry partials -> CAR64.
__global__ __launch_bounds__(512, 4)
void gemm1_kernel(const float* __restrict__ Xf, const ushort_t* __restrict__ Bm,
                  ushort_t* __restrict__ Cb, const float* __restrict__ PW,
                  float* __restrict__ CAR) {
    __shared__ char smem[49152];
    ushort_t (*shA)[4096] = (ushort_t(*)[4096])smem;            // [2][128*32]
    ushort_t (*shB)[8192] = (ushort_t(*)[8192])(smem + 16384);  // [2][256*32]
    constexpr int KD_ = 512, NT = 4, NKT = 16;

    const int tid  = threadIdx.x;
    const int lane = tid & 63;
    const int wv   = tid >> 6;
    const int wr = wv >> 2, wc = wv & 3;
    const int l15 = lane & 15, lq = lane >> 4;

    const int lin = blockIdx.x;
    const int xcd = lin & 7;
    const int j   = lin >> 3;
    const int mt  = xcd * 32 + j / NT;
    const int nt  = j % NT;
    const int m0 = mt * 128;
    const int n0 = nt * 256;
    const int CN = NT * 256;

    f32x4 acc[4][4];
#pragma unroll
    for (int i = 0; i < 4; ++i)
#pragma unroll
        for (int jj = 0; jj < 4; ++jj)
            acc[i][jj] = (f32x4){0.f, 0.f, 0.f, 0.f};

    // A reg-stage map: thread -> (row 0..127, chunk 0..3 of 8 floats)
    const int arow = tid >> 2;
    const int ac   = tid & 3;
    const float* Axg = Xf + (size_t)(m0 + arow) * KD_ + ac * 8;
    const int awoff = arow * 64 + ((ac ^ ((arow >> 1) & 3)) * 16); // bytes

    // B staging (gload_lds, global pre-swizzled)
    const int srB = wv * 32 + (lane >> 2);
    const int sck = (((lane & 3) ^ ((lane >> 3) & 3))) * 8;
    const ushort_t* Bg = Bm + (size_t)(n0 + srB) * KD_ + sck;

    float4 aLo, aHi;
#define GLB_A(t) do { aLo = *(const float4*)(Axg + (size_t)(t) * 32);         \
                      aHi = *(const float4*)(Axg + (size_t)(t) * 32 + 4);     \
                 } while (0)
#define WRITE_A(t) do {                                                       \
        ushort_t tmp[8] = {f2bf(aLo.x), f2bf(aLo.y), f2bf(aLo.z), f2bf(aLo.w),\
                           f2bf(aHi.x), f2bf(aHi.y), f2bf(aHi.z), f2bf(aHi.w)};\
        *(uint4*)((char*)&shA[(t) & 1][0] + awoff) = *(const uint4*)tmp;      \
    } while (0)
#define STAGE_B(t) do {                                                       \
        load16_lds(Bg + (size_t)(t) * 32, &shB[(t) & 1][wv * 1024]);          \
        load16_lds(Bg + (size_t)(t) * 32 + (size_t)16 * KD_,                  \
                   &shB[(t) & 1][wv * 1024 + 512]);                           \
    } while (0)

    const int rdoff = ((lq ^ ((l15 >> 1) & 3))) * 8;
    const int rdA = (wr * 64 + l15) * 32 + rdoff;
    const int rdB = (wc * 64 + l15) * 32 + rdoff;

    // prologue
    GLB_A(0);
    STAGE_B(0); STAGE_B(1);
    WRITE_A(0);
    asm volatile("s_waitcnt vmcnt(2)" ::: "memory");
    asm volatile("s_waitcnt lgkmcnt(0)" ::: "memory");
    __builtin_amdgcn_s_barrier();

#pragma unroll 2
    for (int kt = 0; kt < NKT; ++kt) {
        const int buf = kt & 1;
        bf16x8 af[4], bq[4];
#pragma unroll
        for (int mi = 0; mi < 4; ++mi)
            af[mi] = ldfrag(&shA[buf][rdA + mi * 512]);
#pragma unroll
        for (int ni = 0; ni < 4; ++ni)
            bq[ni] = ldfrag(&shB[buf][rdB + ni * 512]);
        if (kt + 1 < NKT) GLB_A(kt + 1);
        __builtin_amdgcn_s_barrier();
        if (kt + 2 < NKT) STAGE_B(kt + 2);
        if (kt + 1 < NKT) {
            WRITE_A(kt + 1);
            asm volatile("s_waitcnt vmcnt(2)" ::: "memory");
        }
        __builtin_amdgcn_s_setprio(1);
#pragma unroll
        for (int mi = 0; mi < 4; ++mi)
#pragma unroll
            for (int ni = 0; ni < 4; ++ni)
                acc[mi][ni] = __builtin_amdgcn_mfma_f32_16x16x32_bf16(
                    af[mi], bq[ni], acc[mi][ni], 0, 0, 0);
        __builtin_amdgcn_s_setprio(0);
        if (kt + 1 < NKT) {
            asm volatile("s_waitcnt lgkmcnt(0)" ::: "memory");
            __builtin_amdgcn_s_barrier();
        }
    }
#undef GLB_A
#undef WRITE_A
#undef STAGE_B

    // ---- reuse smem as epilogue scratch ----
    asm volatile("s_waitcnt lgkmcnt(0)" ::: "memory");
    __builtin_amdgcn_s_barrier();

    const int rr = lane >> 2;
    const int cc = (lane & 3) * 16;
    {   // bf16 patch [16][72] per wave (144B stride)
        ushort_t* ep = (ushort_t*)(smem + wv * 2304);
#pragma unroll
        for (int mi = 0; mi < 4; ++mi) {
#pragma unroll
            for (int ni = 0; ni < 4; ++ni)
#pragma unroll
                for (int r = 0; r < 4; ++r)
                    ep[(lq * 4 + r) * 72 + ni * 16 + l15] = f2bf(acc[mi][ni][r]);
            uint4 w0 = *(const uint4*)&ep[rr * 72 + cc];
            uint4 w1 = *(const uint4*)&ep[rr * 72 + cc + 8];
            const int rowg = m0 + wr * 64 + mi * 16 + rr;
            *(uint4*)&Cb[(size_t)rowg * CN + n0 + wc * 64 + cc]     = w0;
            *(uint4*)&Cb[(size_t)rowg * CN + n0 + wc * 64 + cc + 8] = w1;
        }
    }

    // ---- fused 64-row carry partials (per wave) -> CAR64 ----
    {
        const int dirq = ((n0 + wc * 64) >> 9) & 1;  // wave-uniform
        const bool evn = ((l15 & 1) == 0);

#define CACC(MI, R, CCo) do {                                                 \
            float vo = bf2f(f2bf(acc[MI][ni][R]));                            \
            float vp = __shfl_xor(vo, 1);                                     \
            float vr = evn ? vo : vp;                                         \
            float vi = evn ? vp : vo;                                         \
            wr_ = fmaf(CCo.x, vr, fmaf(-CCo.y, vi, wr_));                     \
            wi_ = fmaf(CCo.x, vi, fmaf(CCo.y, vr, wi_));                      \
        } while (0)
#define CSTEP(MI) do {                                                        \
            float wr_ = 0.f, wi_ = 0.f;                                       \
            CACC(MI, 0, c0); CACC(MI, 1, c1);                                 \
            CACC(MI, 2, c2); CACC(MI, 3, c3);                                 \
            float comp = evn ? (t16.x * wr_ - t16.y * wi_)                    \
                             : (t16.x * wi_ + t16.y * wr_);                   \
            csum += comp;                                                     \
            t16 = cmul(t16, A16);                                             \
        } while (0)

#pragma unroll
        for (int ni = 0; ni < 4; ++ni) {
            const int col = n0 + wc * 64 + ni * 16 + l15;
            const int q = col >> 1;
            float2 A1  = make_float2(PW[q * 8 + 0], PW[q * 8 + 1]);
            float2 A4  = make_float2(PW[q * 8 + 2], PW[q * 8 + 3]);
            float2 A16 = make_float2(PW[q * 8 + 4], PW[q * 8 + 5]);
            const int lqp = dirq ? lq : 3 - lq;
            float2 A4_2 = cmul(A4, A4);
            float2 A4_3 = cmul(A4_2, A4);
            float2 P4 = (lqp == 0) ? make_float2(1.f, 0.f)
                       : (lqp == 1) ? A4
                       : (lqp == 2) ? A4_2 : A4_3;
            float2 c0, c1, c2, c3;
            if (dirq == 0) {
                c3 = P4; c2 = cmul(c3, A1); c1 = cmul(c2, A1); c0 = cmul(c1, A1);
            } else {
                c0 = P4; c1 = cmul(c0, A1); c2 = cmul(c1, A1); c3 = cmul(c2, A1);
            }
            float2 t16 = make_float2(1.f, 0.f);
            float csum = 0.f;
            if (dirq == 0) { CSTEP(3); CSTEP(2); CSTEP(1); CSTEP(0); }
            else           { CSTEP(0); CSTEP(1); CSTEP(2); CSTEP(3); }
            csum += __shfl_xor(csum, 16);
            csum += __shfl_xor(csum, 32);
            if (lq == 0)
                CAR[(size_t)((m0 >> 6) + wr) * 1024 + col] = csum;
        }
#undef CACC
#undef CSTEP
    }
}

// ---------------------------------------------------------------------------
// Fused scan + GEMM2.  ONLY change this round: __launch_bounds__(512, 2)
// so the register allocator gets the full 256-VGPR budget (the block is
// LDS-bound to 1 block/CU = 2 waves/EU anyway).  R8's reported VGPR=100 with
// ~150 live registers in phase 2 meant ~40-50 spilled regs -> ~320 MB of
// scratch write traffic (the WRITE_SIZE anomaly).  Zero occupancy cost.
__global__ __launch_bounds__(512, 2)
void scan_gemm2_kernel(const ushort_t* __restrict__ SB,
                       const ushort_t* __restrict__ Cm,
                       const float* __restrict__ abar,
                       const float* __restrict__ CAR,
                       const float* __restrict__ Xf,
                       const float* __restrict__ Dv,
                       float* __restrict__ Y) {
    __shared__ char smem[163840];     // A: 0..131072 (64x2048B, swizzled)
                                      // B: 131072..163840 ([4][512][16B])
    const int tid = threadIdx.x;
    const int blk = blockIdx.x;
    const int gm0 = blk * 64;
    const int bidx = blk >> 7;        // batch (128 64-row groups per batch)
    const int hb   = blk & 127;
    const int wv   = tid >> 6;

    // ---------- phase 1a: coalesced SB -> swizzled LDS ----------
    {
        const int cbp = (tid & 127) * 16;        // LDS byte-pos within row
        const char* SBb = (const char*)(SB + (size_t)gm0 * 1024);
#pragma unroll
        for (int L = 0; L < 16; ++L) {
            const int row = L * 4 + (tid >> 7);
            const int src = cbp ^ ((row & 7) << 4);
            load16_lds(SBb + (size_t)row * 2048 + src,
                       smem + L * 8192 + wv * 1024);
        }
    }
    asm volatile("s_waitcnt vmcnt(0)" ::: "memory");
    __syncthreads();

    // ---------- phase 1b: init fold + in-LDS column scan ----------
    {
        const int dir = tid >> 8, p = tid & 255;   // wave-uniform dir
        const int col = dir * 512 + 2 * p;
        const int colb = dir * 1024 + 4 * p;
        float2 a1 = *(const float2*)&abar[col];
        float2 a2 = cmul(a1, a1), a4 = cmul(a2, a2), a8 = cmul(a4, a4);
        float2 a16 = cmul(a8, a8), a32 = cmul(a16, a16), a64 = cmul(a32, a32);

        float sr = 0.f, si = 0.f;                  // exclusive prefix (init)
        if (dir == 0) {
            for (int hc = 0; hc < hb; ++hc) {
                float2 c = *(const float2*)&CAR[(size_t)(bidx * 128 + hc) * 1024 + col];
                float nr = fmaf(a64.x, sr, fmaf(-a64.y, si, c.x));
                float ni = fmaf(a64.x, si, fmaf( a64.y, sr, c.y));
                sr = nr; si = ni;
            }
        } else {
            for (int hc = 127; hc > hb; --hc) {
                float2 c = *(const float2*)&CAR[(size_t)(bidx * 128 + hc) * 1024 + col];
                float nr = fmaf(a64.x, sr, fmaf(-a64.y, si, c.x));
                float ni = fmaf(a64.x, si, fmaf( a64.y, sr, c.y));
                sr = nr; si = ni;
            }
        }

#pragma unroll 8
        for (int ii = 0; ii < 64; ++ii) {
            const int i = dir ? 63 - ii : ii;
            unsigned* ap = (unsigned*)(smem + i * 2048 + (colb ^ ((i & 7) << 4)));
            unsigned u = *ap;
            float re = bf2f((ushort_t)(u & 0xffffu));
            float im = bf2f((ushort_t)(u >> 16));
            float nr = fmaf(a1.x, sr, fmaf(-a1.y, si, re));
            float ni = fmaf(a1.x, si, fmaf( a1.y, sr, im));
            sr = nr; si = ni;
            *ap = ((unsigned)f2bf(si) << 16) | (unsigned)f2bf(sr);
        }
    }
    __syncthreads();

    // ---------- phase 2: GEMM from LDS ----------
    const int lane = tid & 63;
    const int l15 = lane & 15, lq = lane >> 4;
    constexpr int NKT2 = 32;
    char* Blds = smem + 131072;

    f32x4 acc[4][4];
#pragma unroll
    for (int i = 0; i < 4; ++i)
#pragma unroll
        for (int jj = 0; jj < 4; ++jj)
            acc[i][jj] = (f32x4){0.f, 0.f, 0.f, 0.f};

    const ushort_t* Bg = Cm + (size_t)tid * 1024;   // thread owns n = tid
    uint4 bA[4], bB[4];
#define BGLB(dst, t) do { _Pragma("unroll")                                   \
        for (int c = 0; c < 4; ++c)                                           \
            dst[c] = *(const uint4*)(Bg + (size_t)(t) * 32 + c * 8);          \
    } while (0)
#define BWRITE(src) do { _Pragma("unroll")                                    \
        for (int c = 0; c < 4; ++c)                                           \
            *(uint4*)(Blds + c * 8192 + tid * 16) = src[c];                   \
    } while (0)

    BGLB(bA, 0); BGLB(bB, 1);
    BWRITE(bA);
    asm volatile("s_waitcnt lgkmcnt(0)" ::: "memory");
    __builtin_amdgcn_s_barrier();

    const int axk = (l15 & 7) << 4;                  // A swizzle key (bytes)
    for (int t = 0; t < NKT2; ++t) {
        if (t + 2 < NKT2) { if ((t & 1) == 0) BGLB(bA, t + 2); else BGLB(bB, t + 2); }
        bf16x8 af[4], bf[4];
#pragma unroll
        for (int mi = 0; mi < 4; ++mi) {
            const int row = mi * 16 + l15;
            af[mi] = ldfrag((const ushort_t*)(smem +
                        ((row * 2048 + t * 64 + lq * 16) ^ axk)));
        }
#pragma unroll
        for (int ni = 0; ni < 4; ++ni)
            bf[ni] = ldfrag((const ushort_t*)(Blds + lq * 8192 +
                        (wv * 64 + ni * 16 + l15) * 16));
        asm volatile("s_waitcnt lgkmcnt(0)" ::: "memory");
        __builtin_amdgcn_s_barrier();
        if (t + 1 < NKT2) { if ((t & 1) == 0) BWRITE(bB); else BWRITE(bA); }
        __builtin_amdgcn_s_setprio(1);
#pragma unroll
        for (int mi = 0; mi < 4; ++mi)
#pragma unroll
            for (int ni = 0; ni < 4; ++ni)
                acc[mi][ni] = __builtin_amdgcn_mfma_f32_16x16x32_bf16(
                    af[mi], bf[ni], acc[mi][ni], 0, 0, 0);
        __builtin_amdgcn_s_setprio(0);
        if (t + 1 < NKT2) {
            asm volatile("s_waitcnt lgkmcnt(0)" ::: "memory");
            __builtin_amdgcn_s_barrier();
        }
    }
#undef BGLB
#undef BWRITE

    // ---------- phase 3: epilogue ----------
#pragma unroll
    for (int ni = 0; ni < 4; ++ni) {
        const int colY = wv * 64 + ni * 16 + l15;
        const float dsum = Dv[colY] + Dv[512 + colY];
#pragma unroll
        for (int mi = 0; mi < 4; ++mi)
#pragma unroll
            for (int r = 0; r < 4; ++r) {
                const int row = gm0 + mi * 16 + lq * 4 + r;
                const size_t idx = (size_t)row * 512 + colY;
                Y[idx] = acc[mi][ni][r] + Xf[idx] * dsum;
            }
    }
}

// ---------------------------------------------------------------------------
// ws layout (bytes):
//  SB16 : 0           (67,108,864)  [M][1024] bf16 bu (read once)
//  CAR64: 67,108,864  (2,097,152)   [512][1024] f32 64-row carries
//  Bm16 : 100,663,296 (1,048,576)
//  Cm16 : 101,711,872 (1,048,576)
//  abar : 102,760,448 (4,096)
// d_out scratch (dead until scan_gemm2 writes y):
//  PW   : d_out + 0   (16,384)
extern "C" void kernel_launch(void* const* d_in, const int* in_sizes, int n_in,
                              void* d_out, int out_size, void* d_ws, size_t ws_size,
                              hipStream_t stream) {
    const float* x   = (const float*)d_in[0];
    const float* Lre = (const float*)d_in[1];
    const float* Lim = (const float*)d_in[2];
    const float* ldt = (const float*)d_in[3];
    const float* Bre = (const float*)d_in[4];
    const float* Bim = (const float*)d_in[5];
    const float* Cre = (const float*)d_in[6];
    const float* Cim = (const float*)d_in[7];
    const float* Dv  = (const float*)d_in[8];
    float* y = (float*)d_out;
    char* ws = (char*)d_ws;

    ushort_t* SB16  = (ushort_t*)(ws);
    float*    CAR64 = (float*)(ws + 67108864);
    ushort_t* Bm16  = (ushort_t*)(ws + 100663296);
    ushort_t* Cm16  = (ushort_t*)(ws + 101711872);
    float*    abar  = (float*)(ws + 102760448);
    float*    PW    = (float*)d_out;               // dead until final kernel

    prep_kernel<<<1024, 256, 0, stream>>>(Lre, Lim, ldt, Bre, Bim, Cre, Cim,
                                          abar, PW, Bm16, Cm16);

    // GEMM1 (+64-row carry partials): 256 m-tiles x 4 n-tiles, 2 blocks/CU
    gemm1_kernel<<<1024, 512, 0, stream>>>(x, Bm16, SB16, PW, CAR64);

    // fused scan + GEMM2 + D-term: one block per 64 rows
    scan_gemm2_kernel<<<512, 512, 0, stream>>>(SB16, Cm16, abar, CAR64,
                                               x, Dv, y);
}

// Round 10
// 269.926 us; speedup vs baseline: 1.6442x; 1.6442x over previous
//
#include <hip/hip_runtime.h>
#include <math.h>

typedef unsigned short ushort_t;
typedef __bf16 bf16x8 __attribute__((ext_vector_type(8)));
typedef ushort_t ushort8v __attribute__((ext_vector_type(8)));
typedef float f32x4 __attribute__((ext_vector_type(4)));

#define B_SZ   4
#define SEQ    8192
#define M_ROWS (B_SZ * SEQ)   // 32768
#define CH     128
#define NC     (SEQ / CH)     // 64

__device__ __forceinline__ ushort_t f2bf(float f) {
    unsigned u = __float_as_uint(f);
    u = u + 0x7fffu + ((u >> 16) & 1u);
    return (ushort_t)(u >> 16);
}
__device__ __forceinline__ float bf2f(ushort_t b) {
    return __uint_as_float(((unsigned)b) << 16);
}

__device__ __forceinline__ void load16_lds(const void* g, void* l) {
    __builtin_amdgcn_global_load_lds(
        (const __attribute__((address_space(1))) unsigned int*)g,
        (__attribute__((address_space(3))) unsigned int*)l, 16, 0, 0);
}

__device__ __forceinline__ bf16x8 ldfrag(const ushort_t* p) {
    union { ushort8v u; bf16x8 b; } cv;
    cv.u = *(const ushort8v*)p;
    return cv.b;
}

// ---------------------------------------------------------------------------
// Fused prep: per-idx computes one Bmat complex pair and one Cmat pair;
// h==0 threads also write abar/apow.
__global__ void prep_kernel(const float* __restrict__ Lre,
                            const float* __restrict__ Lim,
                            const float* __restrict__ ldt,
                            const float* __restrict__ Bre,
                            const float* __restrict__ Bim,
                            const float* __restrict__ Cre,
                            const float* __restrict__ Cim,
                            float* __restrict__ abar,
                            float* __restrict__ apow,
                            ushort_t* __restrict__ Bmat,
                            ushort_t* __restrict__ Cmat) {
    int idx = blockIdx.x * 256 + threadIdx.x;   // 0 .. 262143
    int h = idx & 511;
    int p = (idx >> 9) & 255;
    int d = idx >> 17;
    int ip = d * 256 + p;
    float lr = Lre[ip], li = Lim[ip];
    float dt = expf(ldt[ip]);
    float e   = expf(lr * dt);
    float ang = li * dt;
    float ar = e * cosf(ang), ai = e * sinf(ang);
    float nr = ar - 1.0f, ni = ai;
    float den = lr * lr + li * li;
    float cr = (nr * lr + ni * li) / den;
    float ci = (ni * lr - nr * li) / den;
    float br = Bre[idx], bi = Bim[idx];
    Bmat[(d * 512 + 2 * p) * 512 + h]     = f2bf(cr * br - ci * bi);
    Bmat[(d * 512 + 2 * p + 1) * 512 + h] = f2bf(cr * bi + ci * br);
    if (h == 0) {
        int o = d * 512 + 2 * p;
        abar[o] = ar;  abar[o + 1] = ai;
        float eC = expf(lr * dt * (float)CH);
        float aC = ang * (float)CH;
        apow[o] = eC * cosf(aC);  apow[o + 1] = eC * sinf(aC);
    }
    int p2 = idx & 255;
    int h2 = (idx >> 8) & 511;
    int d2 = idx >> 17;
    Cmat[h2 * 1024 + d2 * 512 + 2 * p2]     = f2bf(Cre[idx]);
    Cmat[h2 * 1024 + d2 * 512 + 2 * p2 + 1] = f2bf(-Cim[idx]);
}

__global__ void conv_x_kernel(const float* __restrict__ x,
                              ushort_t* __restrict__ X16) {
    int i = blockIdx.x * 256 + threadIdx.x;
    float4 v = ((const float4*)x)[i];
    ushort_t o[4] = {f2bf(v.x), f2bf(v.y), f2bf(v.z), f2bf(v.w)};
    *(uint2*)&X16[(size_t)i * 4] = *(const uint2*)o;
}

// ---------------------------------------------------------------------------
// 256x256 8-phase bf16 GEMM (T2+T3+T4+T5 port, plain HIP).
//   BM=BN=256, BK=64 (2 k-slices of 32), 512 threads = 8 waves (2M x 4N),
//   per-wave output 128x64 -> acc[8][4] f32x4 (128 VGPRs).
// LDS: shA/shB[buf2][ks2][256 rows][32 k] bf16 = 128 KiB total.
// Swizzle (T2): row of 32 bf16 = 4 chunks of 16B; LDS[row][c] holds global
//   chunk (c ^ ((row>>1)&3)).  Applied on the GLOBAL source address (DMA dest
//   stays linear, rule #21) and on the ds_read address.
// Pipeline (T3+T4): 4 phases per K-tile; each phase = {ds_read frags; stage
//   ONE half-slot 2x global_load_lds; s_barrier; setprio(1); 16 MFMA;
//   setprio(0); s_barrier}.  Tile boundary: ONE s_waitcnt vmcnt(6) + barrier;
//   never vmcnt(0) in the main loop.
template<int EPI, int KD_, int NT>
__global__ __launch_bounds__(512, 2)
void gemm_8ph(const ushort_t* __restrict__ A, const ushort_t* __restrict__ Bm,
              ushort_t* __restrict__ Cb, float* __restrict__ Cf,
              const float* __restrict__ X, const float* __restrict__ Dv) {
    __shared__ ushort_t shA[2][2][256 * 32];
    __shared__ ushort_t shB[2][2][256 * 32];
    constexpr int NKT = KD_ / 64;

    const int tid  = threadIdx.x;
    const int lane = tid & 63;
    const int wv   = tid >> 6;
    const int wr = wv >> 2, wc = wv & 3;
    const int l15 = lane & 15, lq = lane >> 4;

    // XCD swizzle: all NT n-tiles of an m-tile adjacent on one XCD.
    const int lin = blockIdx.x;
    const int xcd = lin & 7;
    const int j   = lin >> 3;
    const int mt  = xcd * 16 + j / NT;
    const int nt  = j % NT;
    const int m0 = mt * 256;
    const int n0 = nt * 256;
    const int CN = NT * 256;

    f32x4 acc[8][4];
#pragma unroll
    for (int i = 0; i < 8; ++i)
#pragma unroll
        for (int jj = 0; jj < 4; ++jj)
            acc[i][jj] = (f32x4){0.f, 0.f, 0.f, 0.f};

    // staging: thread -> (row, chunk); LDS dest linear, global src pre-swizzled.
    const int srow = wv * 32 + (lane >> 2);
    const int sck  = (((lane & 3) ^ ((lane >> 3) & 3))) * 8;
    const ushort_t* Ag = A  + (size_t)(m0 + srow) * KD_ + sck;
    const ushort_t* Bg = Bm + (size_t)(n0 + srow) * KD_ + sck;

#define STAGE_A(t, ks) do {                                                   \
        const ushort_t* g_ = Ag + (size_t)(t) * 64 + (ks) * 32;               \
        ushort_t* d_ = &shA[(t) & 1][(ks)][wv * 1024];                        \
        load16_lds(g_, d_);                                                   \
        load16_lds(g_ + (size_t)16 * KD_, d_ + 512);                          \
    } while (0)
#define STAGE_B(t, ks) do {                                                   \
        const ushort_t* g_ = Bg + (size_t)(t) * 64 + (ks) * 32;               \
        ushort_t* d_ = &shB[(t) & 1][(ks)][wv * 1024];                        \
        load16_lds(g_, d_);                                                   \
        load16_lds(g_ + (size_t)16 * KD_, d_ + 512);                          \
    } while (0)

    const int rdoff = ((lq ^ ((l15 >> 1) & 3))) * 8;
    const int rdA = (wr * 128 + l15) * 32 + rdoff;
    const int rdB = (wc * 64  + l15) * 32 + rdoff;

#define MFMA_PH(bx, by, nlo) do {                                             \
        __builtin_amdgcn_s_setprio(1);                                        \
        _Pragma("unroll")                                                     \
        for (int mi_ = 0; mi_ < 8; ++mi_) {                                   \
            acc[mi_][nlo]     = __builtin_amdgcn_mfma_f32_16x16x32_bf16(      \
                af[mi_], bx, acc[mi_][nlo], 0, 0, 0);                         \
            acc[mi_][nlo + 1] = __builtin_amdgcn_mfma_f32_16x16x32_bf16(      \
                af[mi_], by, acc[mi_][nlo + 1], 0, 0, 0);                     \
        }                                                                     \
        __builtin_amdgcn_s_setprio(0);                                        \
    } while (0)

    // prologue: tile0 + {A(1,0), B(1,0), A(1,1)}; vmcnt(6) -> tile0 landed.
    STAGE_A(0, 0); STAGE_A(0, 1); STAGE_B(0, 0); STAGE_B(0, 1);
    STAGE_A(1, 0); STAGE_B(1, 0); STAGE_A(1, 1);
    asm volatile("s_waitcnt vmcnt(6)" ::: "memory");
    __builtin_amdgcn_s_barrier();

    bf16x8 af[8];
#pragma unroll 2
    for (int kt = 0; kt < NKT; ++kt) {
        const int buf = kt & 1;
        const ushort_t* aS0 = &shA[buf][0][rdA];
        const ushort_t* aS1 = &shA[buf][1][rdA];
        const ushort_t* bS0 = &shB[buf][0][rdB];
        const ushort_t* bS1 = &shB[buf][1][rdB];

        { // phase 1: ks0 x ni{0,1}
#pragma unroll
            for (int mi = 0; mi < 8; ++mi) af[mi] = ldfrag(aS0 + mi * 512);
            bf16x8 b0 = ldfrag(bS0), b1 = ldfrag(bS0 + 512);
            if (kt + 1 < NKT) STAGE_B(kt + 1, 1);
            __builtin_amdgcn_s_barrier();
            MFMA_PH(b0, b1, 0);
            __builtin_amdgcn_s_barrier();
        }
        { // phase 2: ks0 x ni{2,3}
            bf16x8 b2 = ldfrag(bS0 + 1024), b3 = ldfrag(bS0 + 1536);
            if (kt + 2 < NKT) STAGE_A(kt + 2, 0);
            __builtin_amdgcn_s_barrier();
            MFMA_PH(b2, b3, 2);
            __builtin_amdgcn_s_barrier();
        }
        { // phase 3: ks1 x ni{0,1}
#pragma unroll
            for (int mi = 0; mi < 8; ++mi) af[mi] = ldfrag(aS1 + mi * 512);
            bf16x8 b0 = ldfrag(bS1), b1 = ldfrag(bS1 + 512);
            if (kt + 2 < NKT) STAGE_B(kt + 2, 0);
            __builtin_amdgcn_s_barrier();
            MFMA_PH(b0, b1, 0);
            __builtin_amdgcn_s_barrier();
        }
        { // phase 4: ks1 x ni{2,3} + tile boundary
            bf16x8 b2 = ldfrag(bS1 + 1024), b3 = ldfrag(bS1 + 1536);
            if (kt + 2 < NKT) STAGE_A(kt + 2, 1);
            __builtin_amdgcn_s_barrier();
            MFMA_PH(b2, b3, 2);
            if (kt + 1 < NKT) {
                if (kt + 2 < NKT)
                    asm volatile("s_waitcnt vmcnt(6)" ::: "memory");
                else
                    asm volatile("s_waitcnt vmcnt(0)" ::: "memory");
                __builtin_amdgcn_s_barrier();
            }
        }
    }
#undef STAGE_A
#undef STAGE_B
#undef MFMA_PH

    // epilogue
#pragma unroll
    for (int mi = 0; mi < 8; ++mi) {
#pragma unroll
        for (int ni = 0; ni < 4; ++ni) {
            const int col = n0 + wc * 64 + ni * 16 + l15;
            float dsum = 0.f;
            if (EPI == 1) dsum = Dv[col] + Dv[512 + col];
#pragma unroll
            for (int r = 0; r < 4; ++r) {
                const int row = m0 + wr * 128 + mi * 16 + lq * 4 + r;
                if (EPI == 0) {
                    Cb[(size_t)row * CN + col] = f2bf(acc[mi][ni][r]);
                } else {
                    const size_t idx = (size_t)row * 512 + col;
                    Cf[idx] = acc[mi][ni][r] + X[idx] * dsum;
                }
            }
        }
    }
}

// ---------------------------------------------------------------------------
// Scans over SB[row][1024], k = dir*512 + 2p(+1). Both dirs per launch:
// threads 0..255 dir0 (forward), 256..511 dir1 (backward).
__global__ __launch_bounds__(512)
void scan_carry(const ushort_t* __restrict__ S, const float* __restrict__ abar,
                float* __restrict__ carry) {
    int b = blockIdx.x, c = blockIdx.y, t = threadIdx.x;
    int dir = t >> 8, p = t & 255;
    float ar = abar[dir * 512 + 2 * p], ai = abar[dir * 512 + 2 * p + 1];
    float sr = 0.f, si = 0.f;
    const ushort_t* base = S + ((size_t)b * SEQ + (size_t)c * CH) * 1024
                             + dir * 512 + 2 * p;
    for (int ii = 0; ii < CH; ++ii) {
        int i = dir ? (CH - 1 - ii) : ii;
        unsigned u = *(const unsigned*)(base + (size_t)i * 1024);
        float re = bf2f((ushort_t)(u & 0xffffu));
        float im = bf2f((ushort_t)(u >> 16));
        float nr = fmaf(ar, sr, fmaf(-ai, si, re));
        float ni = fmaf(ar, si, fmaf(ai, sr, im));
        sr = nr; si = ni;
    }
    int o = (b * NC + c) * 1024 + dir * 512 + 2 * p;
    carry[o] = sr; carry[o + 1] = si;
}

__global__ __launch_bounds__(512)
void scan_comb(const float* __restrict__ carry, float* __restrict__ init,
               const float* __restrict__ apow) {
    int b = blockIdx.x, t = threadIdx.x;
    int dir = t >> 8, p = t & 255;
    float pr = apow[dir * 512 + 2 * p], pi = apow[dir * 512 + 2 * p + 1];
    float sr = 0.f, si = 0.f;
    for (int cc = 0; cc < NC; ++cc) {
        int c = dir ? (NC - 1 - cc) : cc;
        int o = (b * NC + c) * 1024 + dir * 512 + 2 * p;
        init[o] = sr; init[o + 1] = si;
        float cr = carry[o], ci = carry[o + 1];
        float nr = fmaf(pr, sr, fmaf(-pi, si, cr));
        float ni = fmaf(pr, si, fmaf(pi, sr, ci));
        sr = nr; si = ni;
    }
}

__global__ __launch_bounds__(512)
void scan_final(ushort_t* __restrict__ S, const float* __restrict__ abar,
                const float* __restrict__ init) {
    int b = blockIdx.x, c = blockIdx.y, t = threadIdx.x;
    int dir = t >> 8, p = t & 255;
    float ar = abar[dir * 512 + 2 * p], ai = abar[dir * 512 + 2 * p + 1];
    int o = (b * NC + c) * 1024 + dir * 512 + 2 * p;
    float sr = init[o], si = init[o + 1];
    ushort_t* base = S + ((size_t)b * SEQ + (size_t)c * CH) * 1024
                       + dir * 512 + 2 * p;
    for (int ii = 0; ii < CH; ++ii) {
        int i = dir ? (CH - 1 - ii) : ii;
        unsigned* addr = (unsigned*)(base + (size_t)i * 1024);
        unsigned u = *addr;
        float re = bf2f((ushort_t)(u & 0xffffu));
        float im = bf2f((ushort_t)(u >> 16));
        float nr = fmaf(ar, sr, fmaf(-ai, si, re));
        float ni = fmaf(ar, si, fmaf(ai, sr, im));
        sr = nr; si = ni;
        *addr = ((unsigned)f2bf(si) << 16) | (unsigned)f2bf(sr);
    }
}

// ---------------------------------------------------------------------------
// ws layout (bytes):
//  SB16 : 0           (67,108,864)  [M][1024] bf16 states both dirs
//  X16  : 67,108,864  (33,554,432)  bf16 x
//  Bm16 : 100,663,296 (1,048,576)
//  Cm16 : 101,711,872 (1,048,576)
//  abar : 102,760,448 (4,096)
//  apow : 102,764,544 (4,096)
//  carry: 67,108,864  (1,048,576)   alias over X16 head (dead after GEMM1)
//  init : 68,157,440  (1,048,576)   alias
extern "C" void kernel_launch(void* const* d_in, const int* in_sizes, int n_in,
                              void* d_out, int out_size, void* d_ws, size_t ws_size,
                              hipStream_t stream) {
    const float* x   = (const float*)d_in[0];
    const float* Lre = (const float*)d_in[1];
    const float* Lim = (const float*)d_in[2];
    const float* ldt = (const float*)d_in[3];
    const float* Bre = (const float*)d_in[4];
    const float* Bim = (const float*)d_in[5];
    const float* Cre = (const float*)d_in[6];
    const float* Cim = (const float*)d_in[7];
    const float* Dv  = (const float*)d_in[8];
    float* y = (float*)d_out;
    char* ws = (char*)d_ws;

    ushort_t* SB16 = (ushort_t*)(ws);
    ushort_t* X16  = (ushort_t*)(ws + 67108864);
    ushort_t* Bm16 = (ushort_t*)(ws + 100663296);
    ushort_t* Cm16 = (ushort_t*)(ws + 101711872);
    float* abar  = (float*)(ws + 102760448);
    float* apow  = (float*)(ws + 102764544);
    float* carry = (float*)(ws + 67108864);
    float* initb = (float*)(ws + 68157440);

    prep_kernel<<<1024, 256, 0, stream>>>(Lre, Lim, ldt, Bre, Bim, Cre, Cim,
                                          abar, apow, Bm16, Cm16);
    conv_x_kernel<<<16384, 256, 0, stream>>>(x, X16);

    // GEMM1: SB[M][1024] = X16[M][512] * Bm16[1024][512]^T  (128 mt x 4 nt)
    gemm_8ph<0, 512, 4><<<512, 512, 0, stream>>>(X16, Bm16, SB16, nullptr,
                                                 nullptr, nullptr);

    dim3 gs(B_SZ, NC);
    scan_carry<<<gs, 512, 0, stream>>>(SB16, abar, carry);
    scan_comb<<<B_SZ, 512, 0, stream>>>(carry, initb, apow);
    scan_final<<<gs, 512, 0, stream>>>(SB16, abar, initb);

    // GEMM2: y[M][512] = SB16[M][1024] * Cm16[512][1024]^T + x*(D0+D1)
    gemm_8ph<1, 1024, 2><<<256, 512, 0, stream>>>(SB16, Cm16, nullptr, y,
                                                  x, Dv);
}